// Round 9
// baseline (910.257 us; speedup 1.0000x reference)
//
#include <hip/hip_runtime.h>

// GNNModel fused, R9 = R8 structure with __launch_bounds__(256,3).
// R8 postmortem: (256,4) = 128 unified VGPR cap vs ~100-VGPR live set
// (half4v = 2 VGPRs; h[2][8]+hn[2][8] = 64 VGPRs alone) -> 1.2 GB scratch
// WRITE, 0.55 GB refill FETCH. (256,3) = 170 unified. No barriers, no
// loop-carried prefetch -> allocator unconstrained, should fit spill-free.
//
// Register-resident pipeline on v_mfma_f32_16x16x16f16: C/D layout ==
// A/B layout (col=lane&15, row/k=4*(lane>>4)+i) -> MFMA chains with zero
// cross-lane movement. Wave = 2 batches; Ahat B-frag built by shfl
// (bit-exact fp32 mask, A=mask+eye diag 2, Ahat symmetric). Zero LDS and
// zero barriers in proj+layers; wave-private LDS tail for pool/head.

typedef _Float16 half4v __attribute__((ext_vector_type(4)));
typedef _Float16 half8v __attribute__((ext_vector_type(8)));
typedef float    float4v __attribute__((ext_vector_type(4)));

constexpr int PP = 12, DIN = 32, H = 128, HO = 64, DOUT = 3, NL = 3;
// ws layout (halves):
//   wsP [mt=8][lane=64][8]  : Win^T A-frags (j<4: kt=0, j>=4: kt=1)
//   wsG [l=3][nt=8][ktp=4][lane=64][8] : W B-frags (halves j<4: kt=2ktp, j>=4: 2ktp+1)
//   wsH1 [o=64][k=128]      : W_out1^T rows
constexpr int WSP_OFF = 0, WSG_OFF = 4096, WSH_OFF = 53248, WS_TOT = 61440;

__global__ __launch_bounds__(256)
void prep_weights(const float* __restrict__ W_in, const float* __restrict__ W_gcn,
                  const float* __restrict__ W_out1, _Float16* __restrict__ ws)
{
    int e = blockIdx.x * 256 + threadIdx.x;
    if (e < WSG_OFF) {                         // wsP
        int mt = e >> 9, lane = (e >> 3) & 63, hh = e & 7;
        int q = lane >> 4, qm = lane & 15;
        int din = 16 * (hh >> 2) + 4 * q + (hh & 3);
        ws[e] = (_Float16)W_in[din * H + 16 * mt + qm];
    } else if (e < WSH_OFF) {                  // wsG
        int e2 = e - WSG_OFF;
        int l = e2 >> 14, r = e2 & 16383;
        int nt = r >> 11, ktp = (r >> 9) & 3, lane = (r >> 3) & 63, hh = r & 7;
        int q = lane >> 4, qm = lane & 15;
        int hi = 32 * ktp + 16 * (hh >> 2) + 4 * q + (hh & 3);
        ws[e] = (_Float16)W_gcn[l * (H * H) + hi * H + 16 * nt + qm];
    } else if (e < WS_TOT) {                   // wsH1
        int e3 = e - WSH_OFF;
        int o = e3 >> 7, k = e3 & 127;
        ws[e] = (_Float16)W_out1[k * HO + o];
    }
}

__device__ inline half4v lo4(half8v v) { return __builtin_shufflevector(v, v, 0, 1, 2, 3); }
__device__ inline half4v hi4(half8v v) { return __builtin_shufflevector(v, v, 4, 5, 6, 7); }
__device__ inline half4v pk4(float a, float b, float c, float d) {
    half4v r; r[0] = (_Float16)a; r[1] = (_Float16)b; r[2] = (_Float16)c; r[3] = (_Float16)d;
    return r;
}

__global__ __launch_bounds__(256, 3)
void gnn_mfma(const float* __restrict__ x,
              const float* __restrict__ b_in,
              const float* __restrict__ b_gcn,
              const float* __restrict__ b_out1,
              const float* __restrict__ W_out2,
              const float* __restrict__ b_out2,
              const _Float16* __restrict__ ws,
              float* __restrict__ out)
{
    __shared__ _Float16 h3s[4][2][PP][136];    // 25.5 KB, wave-private tail dump
    __shared__ float    g_s[4][2][H];          // 4 KB

    const int tid = threadIdx.x, lane = tid & 63, wave = tid >> 6;
    const int q = lane >> 4, qm = lane & 15;
    const int bb = blockIdx.x * 8 + wave * 2;  // this wave's 2 batches
    const int pcl = (qm < PP) ? qm : (PP - 1); // planet clamp (rows 12..15 dup 11)

    // ---- adjacency B-frags af[b]: B[k=4q+j][n=qm] = Ahat_b[4q+j][qm] (sym) ----
    float lon_own = x[((size_t)bb + (q & 1)) * (PP * DIN) + pcl * DIN];
    float deg = 1.0f;
    #pragma unroll
    for (int j = 0; j < PP; ++j) {
        float lj = __shfl(lon_own, ((q & 1) << 4) + j, 64);
        float d = fabsf(lon_own - lj);
        d = fminf(d, 360.0f - d);
        deg += (d < 10.0f) ? 1.0f : 0.0f;
    }
    float dinv_own = __frsqrt_rn(fmaxf(deg, 1e-12f));
    half4v af[2];
    #pragma unroll
    for (int b = 0; b < 2; ++b) {
        float lon_n = __shfl(lon_own, (b << 4) + qm, 64);
        float dv_n  = __shfl(dinv_own, (b << 4) + qm, 64);
        half4v a;
        #pragma unroll
        for (int j = 0; j < 4; ++j) {
            int p = 4 * q + j;
            float lon_k = __shfl(lon_own, (b << 4) + p, 64);
            float dv_k  = __shfl(dinv_own, (b << 4) + p, 64);
            float d = fabsf(lon_k - lon_n);
            d = fminf(d, 360.0f - d);
            float m = (d < 10.0f) ? 1.0f : 0.0f;
            if (p == qm) m += 1.0f;
            float v = (p < PP && qm < PP) ? m * dv_k * dv_n : 0.0f;
            a[j] = (_Float16)v;
        }
        af[b] = a;
    }

    // ---- proj: h0^T = Win^T @ X^T  (C chains straight into h-frags) ----
    half4v h[2][8];                             // h-frags: A[m=planet(qm)][k=ho]
    {
        half4v bx[2][2];                        // x B-frags: B[k=din][n=planet]
        #pragma unroll
        for (int nt = 0; nt < 2; ++nt) {
            const float* xp = x + ((size_t)(bb + nt)) * (PP * DIN) + pcl * DIN;
            float4 v0 = *(const float4*)&xp[4 * q];
            float4 v1 = *(const float4*)&xp[16 + 4 * q];
            bx[nt][0] = pk4(v0.x, v0.y, v0.z, v0.w);
            bx[nt][1] = pk4(v1.x, v1.y, v1.z, v1.w);
        }
        #pragma unroll
        for (int mt = 0; mt < 8; ++mt) {
            half8v wa = *(const half8v*)&ws[WSP_OFF + (mt * 64 + lane) * 8];
            float4 bi = *(const float4*)&b_in[16 * mt + 4 * q];
            #pragma unroll
            for (int nt = 0; nt < 2; ++nt) {
                float4v c = {0.f, 0.f, 0.f, 0.f};
                c = __builtin_amdgcn_mfma_f32_16x16x16f16(lo4(wa), bx[nt][0], c, 0, 0, 0);
                c = __builtin_amdgcn_mfma_f32_16x16x16f16(hi4(wa), bx[nt][1], c, 0, 0, 0);
                h[nt][mt] = pk4(c[0] + bi.x, c[1] + bi.y, c[2] + bi.z, c[3] + bi.w);
            }
        }
    }

    // ---- GCN layers: zero LDS, zero barriers ----
    #pragma unroll
    for (int l = 0; l < NL; ++l) {
        const _Float16* wg = ws + WSG_OFF + l * 16384;
        half4v hn[2][8];
        #pragma unroll
        for (int nt = 0; nt < 8; ++nt) {
            float4v a0 = {0.f, 0.f, 0.f, 0.f}, a1 = {0.f, 0.f, 0.f, 0.f};
            #pragma unroll
            for (int ktp = 0; ktp < 4; ++ktp) {
                half8v w8 = *(const half8v*)&wg[(nt * 4 + ktp) * 512 + lane * 8];
                a0 = __builtin_amdgcn_mfma_f32_16x16x16f16(h[0][2 * ktp],     lo4(w8), a0, 0, 0, 0);
                a1 = __builtin_amdgcn_mfma_f32_16x16x16f16(h[1][2 * ktp],     lo4(w8), a1, 0, 0, 0);
                a0 = __builtin_amdgcn_mfma_f32_16x16x16f16(h[0][2 * ktp + 1], hi4(w8), a0, 0, 0, 0);
                a1 = __builtin_amdgcn_mfma_f32_16x16x16f16(h[1][2 * ktp + 1], hi4(w8), a1, 0, 0, 0);
            }
            float4 bg = *(const float4*)&b_gcn[l * H + 16 * nt + 4 * q];
            #pragma unroll
            for (int b = 0; b < 2; ++b) {
                float4v t = b ? a1 : a0;
                half4v tp = pk4(t[0], t[1], t[2], t[3]);     // t C-tile -> mix A-frag (t^T)
                float4v d = {0.f, 0.f, 0.f, 0.f};
                d = __builtin_amdgcn_mfma_f32_16x16x16f16(tp, af[b], d, 0, 0, 0);
                hn[b][nt] = pk4(fmaxf(d[0] + bg.x, 0.f), fmaxf(d[1] + bg.y, 0.f),
                                fmaxf(d[2] + bg.z, 0.f), fmaxf(d[3] + bg.w, 0.f));
            }
        }
        #pragma unroll
        for (int b = 0; b < 2; ++b)
            #pragma unroll
            for (int nt = 0; nt < 8; ++nt)
                h[b][nt] = hn[b][nt];
    }

    // ---- once-per-wave tail (wave-private LDS; no barriers needed) ----
    #pragma unroll
    for (int b = 0; b < 2; ++b)
        #pragma unroll
        for (int nt = 0; nt < 8; ++nt)
            if (qm < PP)
                *(half4v*)&h3s[wave][b][qm][16 * nt + 4 * q] = h[b][nt];

    float o1[2];
    #pragma unroll
    for (int b = 0; b < 2; ++b) {
        float s0 = 0.f, s1 = 0.f;
        #pragma unroll
        for (int p = 0; p < PP; ++p) {
            s0 += (float)h3s[wave][b][p][lane];
            s1 += (float)h3s[wave][b][p][lane + 64];
        }
        g_s[wave][b][lane]      = s0 * (1.0f / 12.0f);
        g_s[wave][b][lane + 64] = s1 * (1.0f / 12.0f);
    }
    #pragma unroll
    for (int b = 0; b < 2; ++b) {
        float acc = b_out1[lane];
        const _Float16* wr = ws + WSH_OFF + lane * H;
        #pragma unroll
        for (int kk = 0; kk < H / 8; ++kk) {
            half8v wv = *(const half8v*)&wr[8 * kk];
            #pragma unroll
            for (int j = 0; j < 8; ++j) acc += g_s[wave][b][8 * kk + j] * (float)wv[j];
        }
        o1[b] = fmaxf(acc, 0.f);
    }
    float w20 = W_out2[lane * DOUT + 0];
    float w21 = W_out2[lane * DOUT + 1];
    float w22 = W_out2[lane * DOUT + 2];
    #pragma unroll
    for (int b = 0; b < 2; ++b) {
        float p0 = o1[b] * w20, p1 = o1[b] * w21, p2 = o1[b] * w22;
        #pragma unroll
        for (int off = 32; off > 0; off >>= 1) {
            p0 += __shfl_down(p0, off, 64);
            p1 += __shfl_down(p1, off, 64);
            p2 += __shfl_down(p2, off, 64);
        }
        if (lane == 0) {
            float* o = out + (size_t)(bb + b) * DOUT;
            o[0] = p0 + b_out2[0];
            o[1] = p1 + b_out2[1];
            o[2] = p2 + b_out2[2];
        }
    }
}

extern "C" void kernel_launch(void* const* d_in, const int* in_sizes, int n_in,
                              void* d_out, int out_size, void* d_ws, size_t ws_size,
                              hipStream_t stream) {
    const float* x      = (const float*)d_in[0];
    const float* W_in   = (const float*)d_in[1];
    const float* b_in   = (const float*)d_in[2];
    const float* W_gcn  = (const float*)d_in[3];
    const float* b_gcn  = (const float*)d_in[4];
    const float* W_out1 = (const float*)d_in[5];
    const float* b_out1 = (const float*)d_in[6];
    const float* W_out2 = (const float*)d_in[7];
    const float* b_out2 = (const float*)d_in[8];
    float* outp         = (float*)d_out;
    _Float16* wsh       = (_Float16*)d_ws;

    const int B = in_sizes[0] / (PP * DIN);    // 65536

    hipLaunchKernelGGL(prep_weights, dim3((WS_TOT + 255) / 256), dim3(256), 0, stream,
                       W_in, W_gcn, W_out1, wsh);
    hipLaunchKernelGGL(gnn_mfma, dim3(B / 8), dim3(256), 0, stream,
                       x, b_in, b_gcn, b_out1, W_out2, b_out2, wsh, outp);
}

// Round 10
// 706.074 us; speedup vs baseline: 1.2892x; 1.2892x over previous
//
#include <hip/hip_runtime.h>

// GNNModel fused, R10: register-resident 16x16x16 MFMA chain (R8/R9 math,
// verified) with W fed from LDS. R9 postmortem: spills came from the
// scheduler hoisting 32 global b128 W-loads per layer (~128 VGPRs in
// flight), not from h/hn. Staging W into LDS (32 KB/layer, once per block)
// turns those into short-latency ds_read_b128 -> live set ~110 fits
// (256,3)=170. Tail reuses wbuf (WAR barrier) as the h3 dump. 6 barriers.

typedef _Float16 half4v __attribute__((ext_vector_type(4)));
typedef _Float16 half8v __attribute__((ext_vector_type(8)));
typedef float    float4v __attribute__((ext_vector_type(4)));

constexpr int PP = 12, DIN = 32, H = 128, HO = 64, DOUT = 3, NL = 3;
// ws layout (halves):
//   wsP [mt=8][lane=64][8]  : Win^T A-frags (j<4: kt=0, j>=4: kt=1)
//   wsG [l=3][nt=8][ktp=4][lane=64][8] : W B-frags (j<4: kt=2ktp, j>=4: 2ktp+1)
//   wsH1 [o=64][k=128]      : W_out1^T rows
constexpr int WSP_OFF = 0, WSG_OFF = 4096, WSH_OFF = 53248, WS_TOT = 61440;

__global__ __launch_bounds__(256)
void prep_weights(const float* __restrict__ W_in, const float* __restrict__ W_gcn,
                  const float* __restrict__ W_out1, _Float16* __restrict__ ws)
{
    int e = blockIdx.x * 256 + threadIdx.x;
    if (e < WSG_OFF) {                         // wsP
        int mt = e >> 9, lane = (e >> 3) & 63, hh = e & 7;
        int q = lane >> 4, qm = lane & 15;
        int din = 16 * (hh >> 2) + 4 * q + (hh & 3);
        ws[e] = (_Float16)W_in[din * H + 16 * mt + qm];
    } else if (e < WSH_OFF) {                  // wsG
        int e2 = e - WSG_OFF;
        int l = e2 >> 14, r = e2 & 16383;
        int nt = r >> 11, ktp = (r >> 9) & 3, lane = (r >> 3) & 63, hh = r & 7;
        int q = lane >> 4, qm = lane & 15;
        int hi = 32 * ktp + 16 * (hh >> 2) + 4 * q + (hh & 3);
        ws[e] = (_Float16)W_gcn[l * (H * H) + hi * H + 16 * nt + qm];
    } else if (e < WS_TOT) {                   // wsH1
        int e3 = e - WSH_OFF;
        int o = e3 >> 7, k = e3 & 127;
        ws[e] = (_Float16)W_out1[k * HO + o];
    }
}

__device__ inline half4v lo4(half8v v) { return __builtin_shufflevector(v, v, 0, 1, 2, 3); }
__device__ inline half4v hi4(half8v v) { return __builtin_shufflevector(v, v, 4, 5, 6, 7); }
__device__ inline half4v pk4(float a, float b, float c, float d) {
    half4v r; r[0] = (_Float16)a; r[1] = (_Float16)b; r[2] = (_Float16)c; r[3] = (_Float16)d;
    return r;
}

__global__ __launch_bounds__(256, 3)
void gnn_mfma(const float* __restrict__ x,
              const float* __restrict__ b_in,
              const float* __restrict__ b_gcn,
              const float* __restrict__ b_out1,
              const float* __restrict__ W_out2,
              const float* __restrict__ b_out2,
              const _Float16* __restrict__ ws,
              float* __restrict__ out)
{
    __shared__ _Float16 wbuf[H * H];           // 32 KB: one layer's W frags; tail h-dump alias
    __shared__ float    g_s[4][2][H];          // 4 KB

    const int tid = threadIdx.x, lane = tid & 63, wave = tid >> 6;
    const int q = lane >> 4, qm = lane & 15;
    const int bb = blockIdx.x * 8 + wave * 2;  // this wave's 2 batches
    const int pcl = (qm < PP) ? qm : (PP - 1); // planet clamp (rows 12..15 dup 11)

    // ---- stage layer-0 W into LDS (linear copy of packed frags) ----
    #pragma unroll
    for (int i = 0; i < 8; ++i)
        *(half8v*)&wbuf[i * 2048 + tid * 8] =
            *(const half8v*)&ws[WSG_OFF + i * 2048 + tid * 8];

    // ---- adjacency B-frags af[b] (bit-exact fp32 mask; A=mask+eye, diag 2) ----
    float lon_own = x[((size_t)bb + (q & 1)) * (PP * DIN) + pcl * DIN];
    float deg = 1.0f;
    #pragma unroll
    for (int j = 0; j < PP; ++j) {
        float lj = __shfl(lon_own, ((q & 1) << 4) + j, 64);
        float d = fabsf(lon_own - lj);
        d = fminf(d, 360.0f - d);
        deg += (d < 10.0f) ? 1.0f : 0.0f;
    }
    float dinv_own = __frsqrt_rn(fmaxf(deg, 1e-12f));
    half4v af[2];
    #pragma unroll
    for (int b = 0; b < 2; ++b) {
        float lon_n = __shfl(lon_own, (b << 4) + qm, 64);
        float dv_n  = __shfl(dinv_own, (b << 4) + qm, 64);
        half4v a;
        #pragma unroll
        for (int j = 0; j < 4; ++j) {
            int p = 4 * q + j;
            float lon_k = __shfl(lon_own, (b << 4) + p, 64);
            float dv_k  = __shfl(dinv_own, (b << 4) + p, 64);
            float d = fabsf(lon_k - lon_n);
            d = fminf(d, 360.0f - d);
            float m = (d < 10.0f) ? 1.0f : 0.0f;
            if (p == qm) m += 1.0f;
            float v = (p < PP && qm < PP) ? m * dv_k * dv_n : 0.0f;
            a[j] = (_Float16)v;
        }
        af[b] = a;
    }

    // ---- proj: h0^T = Win^T @ X^T (frags from global; overlaps staging) ----
    half4v h[2][8];
    {
        half4v bx[2][2];
        #pragma unroll
        for (int nt = 0; nt < 2; ++nt) {
            const float* xp = x + ((size_t)(bb + nt)) * (PP * DIN) + pcl * DIN;
            float4 v0 = *(const float4*)&xp[4 * q];
            float4 v1 = *(const float4*)&xp[16 + 4 * q];
            bx[nt][0] = pk4(v0.x, v0.y, v0.z, v0.w);
            bx[nt][1] = pk4(v1.x, v1.y, v1.z, v1.w);
        }
        #pragma unroll
        for (int mt = 0; mt < 8; ++mt) {
            half8v wa = *(const half8v*)&ws[WSP_OFF + (mt * 64 + lane) * 8];
            float4 bi = *(const float4*)&b_in[16 * mt + 4 * q];
            #pragma unroll
            for (int nt = 0; nt < 2; ++nt) {
                float4v c = {0.f, 0.f, 0.f, 0.f};
                c = __builtin_amdgcn_mfma_f32_16x16x16f16(lo4(wa), bx[nt][0], c, 0, 0, 0);
                c = __builtin_amdgcn_mfma_f32_16x16x16f16(hi4(wa), bx[nt][1], c, 0, 0, 0);
                h[nt][mt] = pk4(c[0] + bi.x, c[1] + bi.y, c[2] + bi.z, c[3] + bi.w);
            }
        }
    }
    __syncthreads();   // B1: wbuf(layer 0) staged

    // ---- GCN layers: W B-frags from LDS; h/hn register-resident ----
    #pragma unroll
    for (int l = 0; l < NL; ++l) {
        half4v hn[2][8];
        #pragma unroll
        for (int nt = 0; nt < 8; ++nt) {
            float4v a0 = {0.f, 0.f, 0.f, 0.f}, a1 = {0.f, 0.f, 0.f, 0.f};
            #pragma unroll
            for (int ktp = 0; ktp < 4; ++ktp) {
                half8v w8 = *(const half8v*)&wbuf[(nt * 4 + ktp) * 512 + lane * 8];
                a0 = __builtin_amdgcn_mfma_f32_16x16x16f16(h[0][2 * ktp],     lo4(w8), a0, 0, 0, 0);
                a1 = __builtin_amdgcn_mfma_f32_16x16x16f16(h[1][2 * ktp],     lo4(w8), a1, 0, 0, 0);
                a0 = __builtin_amdgcn_mfma_f32_16x16x16f16(h[0][2 * ktp + 1], hi4(w8), a0, 0, 0, 0);
                a1 = __builtin_amdgcn_mfma_f32_16x16x16f16(h[1][2 * ktp + 1], hi4(w8), a1, 0, 0, 0);
            }
            float4 bg = *(const float4*)&b_gcn[l * H + 16 * nt + 4 * q];
            #pragma unroll
            for (int b = 0; b < 2; ++b) {
                float4v t = b ? a1 : a0;
                half4v tp = pk4(t[0], t[1], t[2], t[3]);     // t C-tile -> mix A-frag (t^T)
                float4v d = {0.f, 0.f, 0.f, 0.f};
                d = __builtin_amdgcn_mfma_f32_16x16x16f16(tp, af[b], d, 0, 0, 0);
                hn[b][nt] = pk4(fmaxf(d[0] + bg.x, 0.f), fmaxf(d[1] + bg.y, 0.f),
                                fmaxf(d[2] + bg.z, 0.f), fmaxf(d[3] + bg.w, 0.f));
            }
        }
        #pragma unroll
        for (int b = 0; b < 2; ++b)
            #pragma unroll
            for (int nt = 0; nt < 8; ++nt)
                h[b][nt] = hn[b][nt];

        __syncthreads();                       // WAR: all waves done reading wbuf
        if (l + 1 < NL) {
            #pragma unroll
            for (int i = 0; i < 8; ++i)
                *(half8v*)&wbuf[i * 2048 + tid * 8] =
                    *(const half8v*)&ws[WSG_OFF + (l + 1) * 16384 + i * 2048 + tid * 8];
            __syncthreads();                   // RAW: next layer's wbuf ready
        }
    }

    // ---- tail: wbuf dead (post-WAR barrier) -> wave-private h dump ----
    _Float16 (*h3s)[2][PP][136] = (_Float16 (*)[2][PP][136])wbuf;   // 25.5 KB <= 32 KB
    #pragma unroll
    for (int b = 0; b < 2; ++b)
        #pragma unroll
        for (int nt = 0; nt < 8; ++nt)
            if (qm < PP)
                *(half4v*)&h3s[wave][b][qm][16 * nt + 4 * q] = h[b][nt];

    float o1[2];
    #pragma unroll
    for (int b = 0; b < 2; ++b) {
        float s0 = 0.f, s1 = 0.f;
        #pragma unroll
        for (int p = 0; p < PP; ++p) {
            s0 += (float)h3s[wave][b][p][lane];
            s1 += (float)h3s[wave][b][p][lane + 64];
        }
        g_s[wave][b][lane]      = s0 * (1.0f / 12.0f);
        g_s[wave][b][lane + 64] = s1 * (1.0f / 12.0f);
    }
    #pragma unroll
    for (int b = 0; b < 2; ++b) {
        float acc = b_out1[lane];
        const _Float16* wr = ws + WSH_OFF + lane * H;
        #pragma unroll
        for (int kk = 0; kk < H / 8; ++kk) {
            half8v wv = *(const half8v*)&wr[8 * kk];
            #pragma unroll
            for (int j = 0; j < 8; ++j) acc += g_s[wave][b][8 * kk + j] * (float)wv[j];
        }
        o1[b] = fmaxf(acc, 0.f);
    }
    float w20 = W_out2[lane * DOUT + 0];
    float w21 = W_out2[lane * DOUT + 1];
    float w22 = W_out2[lane * DOUT + 2];
    #pragma unroll
    for (int b = 0; b < 2; ++b) {
        float p0 = o1[b] * w20, p1 = o1[b] * w21, p2 = o1[b] * w22;
        #pragma unroll
        for (int off = 32; off > 0; off >>= 1) {
            p0 += __shfl_down(p0, off, 64);
            p1 += __shfl_down(p1, off, 64);
            p2 += __shfl_down(p2, off, 64);
        }
        if (lane == 0) {
            float* o = out + (size_t)(bb + b) * DOUT;
            o[0] = p0 + b_out2[0];
            o[1] = p1 + b_out2[1];
            o[2] = p2 + b_out2[2];
        }
    }
}

extern "C" void kernel_launch(void* const* d_in, const int* in_sizes, int n_in,
                              void* d_out, int out_size, void* d_ws, size_t ws_size,
                              hipStream_t stream) {
    const float* x      = (const float*)d_in[0];
    const float* W_in   = (const float*)d_in[1];
    const float* b_in   = (const float*)d_in[2];
    const float* W_gcn  = (const float*)d_in[3];
    const float* b_gcn  = (const float*)d_in[4];
    const float* W_out1 = (const float*)d_in[5];
    const float* b_out1 = (const float*)d_in[6];
    const float* W_out2 = (const float*)d_in[7];
    const float* b_out2 = (const float*)d_in[8];
    float* outp         = (float*)d_out;
    _Float16* wsh       = (_Float16*)d_ws;

    const int B = in_sizes[0] / (PP * DIN);    // 65536

    hipLaunchKernelGGL(prep_weights, dim3((WS_TOT + 255) / 256), dim3(256), 0, stream,
                       W_in, W_gcn, W_out1, wsh);
    hipLaunchKernelGGL(gnn_mfma, dim3(B / 8), dim3(256), 0, stream,
                       x, b_in, b_gcn, b_out1, W_out2, b_out2, wsh, outp);
}